// Round 20
// baseline (80.217 us; speedup 1.0000x reference)
//
#include <hip/hip_runtime.h>
#include <hip/hip_bf16.h>

#define N_POS 4096
#define C_IN 64
#define IC 32
#define L2E 1.4426950408889634f

typedef float f32x16 __attribute__((ext_vector_type(16)));
typedef short bf16x8 __attribute__((ext_vector_type(8)));
typedef unsigned int uint;
typedef uint uint4v __attribute__((ext_vector_type(4)));
typedef unsigned short ushort;

static __device__ __forceinline__ ushort f2bf(float f) {
    __hip_bfloat16 h = __float2bfloat16(f);
    return __builtin_bit_cast(ushort, h);
}
static __device__ __forceinline__ uint packbf2(float lo, float hi) {
    return (uint)f2bf(lo) | ((uint)f2bf(hi) << 16);
}
// truncating pack in ONE v_perm_b32: D = [hi.b3, hi.b2, lo.b3, lo.b2]
static __device__ __forceinline__ uint packtrunc(float lo, float hi) {
    return __builtin_amdgcn_perm(__builtin_bit_cast(uint, hi),
                                 __builtin_bit_cast(uint, lo), 0x07060302u);
}

// ---------------- Stage A: projections -> bf16 MFMA layouts ----------------
// grid (256, 12): gy = proj*4 + q8. theta pre-scaled by log2(e).
// gy==0 blocks 0..63 also do mb prep (folded).
__global__ __launch_bounds__(128) void proj_kernel(
    const float* __restrict__ x,
    const float* __restrict__ g_w, const float* __restrict__ g_b,
    const float* __restrict__ th_w, const float* __restrict__ th_b,
    const float* __restrict__ ph_w, const float* __restrict__ ph_b,
    const float* __restrict__ mb,
    ushort* __restrict__ gcn, ushort* __restrict__ tht, ushort* __restrict__ pht,
    ushort* __restrict__ mbt, ushort* __restrict__ mbb)
{
    int gy = blockIdx.y;
    int pj = gy >> 2, q8 = gy & 3;     // projection, 8-channel quarter
    const float* wsrc = (pj == 0) ? g_w : (pj == 1) ? th_w : ph_w;
    const float* bsrc = (pj == 0) ? g_b : (pj == 1) ? th_b : ph_b;
    __shared__ float w[8][64];
    __shared__ float bias[8];
    int tid = threadIdx.x;
    for (int i = tid; i < 512; i += 128) w[i >> 6][i & 63] = wsrc[q8 * 512 + i];
    if (tid < 8) bias[tid] = bsrc[q8 * 8 + tid];
    __syncthreads();

    int ng = blockIdx.x * 128 + tid;
    int b = ng >> 12, n = ng & 4095;
    const float* xb = x + (size_t)b * C_IN * N_POS + n;
    float xr[64];
    #pragma unroll
    for (int c = 0; c < 64; c++) xr[c] = xb[(size_t)c * N_POS];

    float acc[8];
    #pragma unroll
    for (int o = 0; o < 8; o++) {
        float a = bias[o];
        const float4* w4 = (const float4*)w[o];
        #pragma unroll
        for (int c4 = 0; c4 < 16; c4++) {
            float4 wv = w4[c4];
            a += wv.x * xr[c4*4+0] + wv.y * xr[c4*4+1]
               + wv.z * xr[c4*4+2] + wv.w * xr[c4*4+3];
        }
        if (pj == 1) a *= L2E;
        acc[o] = a;
    }

    if (pj == 0) {
        #pragma unroll
        for (int c = 0; c < 8; c++)
            gcn[((size_t)(b * IC + q8 * 8 + c)) * N_POS + n] = f2bf(acc[c]);
    } else {
        ushort* dst = ((pj == 1) ? tht : pht) + ((size_t)(b * N_POS + n)) * IC + q8 * 8;
        uint4v pk;
        #pragma unroll
        for (int i = 0; i < 4; i++) pk[i] = packbf2(acc[2*i], acc[2*i+1]);
        *(uint4v*)dst = pk;
    }

    if (gy == 0 && blockIdx.x < 64) {
        int i = blockIdx.x * 128 + tid;
        int c = i >> 8, k = i & 255;
        float v = mb[i];
        mbb[i] = f2bf(v);
        mbt[k * 32 + c] = f2bf(v * (0.17677669529663687f * L2E));
    }
}

// ------------- Stage B: non-local attention, q-QUAD amortization ------------
// grid 512 blocks x 4 waves (256 thr): block = (b, qq 0..31, mh 0..1).
// Wave s: keys (mh*4+s)*512 .. +512, FOUR 32-query tiles (phi/g loads
// amortize 4x). Two-phase LDS reduce (38 KB) -> fp32 partial to yp/dnm.
__global__ __launch_bounds__(256) void attn_kernel(
    const ushort* __restrict__ tht, const ushort* __restrict__ pht,
    const ushort* __restrict__ gcn, float* __restrict__ yp,
    float* __restrict__ dnm)
{
    __shared__ float redY[2][4][32][36];   // 36 KB
    __shared__ float redD[4][4][32];       // 2 KB
    int tid = threadIdx.x;
    int s = tid >> 6, lane = tid & 63;
    int bid = blockIdx.x;
    int b = bid & 7;                 // batch -> XCD locality
    int rest = bid >> 3;             // 0..63
    int qq = rest >> 1;              // 0..31
    int mh = rest & 1;
    int q0 = qq * 128;
    int mbase = (mh * 4 + s) * 512;
    int cl = lane & 31, h = lane >> 5;
    int t4 = (cl >> 2) & 3;
    int pcl = (t4 == 1 || t4 == 2) ? (cl ^ 12) : cl;   // pi row permutation

    const ushort* thp = tht + ((size_t)(b * N_POS + q0 + cl)) * IC + 8 * h;
    bf16x8 th00 = *(const bf16x8*)thp;
    bf16x8 th01 = *(const bf16x8*)(thp + 16);
    bf16x8 th10 = *(const bf16x8*)(thp + 32 * IC);
    bf16x8 th11 = *(const bf16x8*)(thp + 32 * IC + 16);
    bf16x8 th20 = *(const bf16x8*)(thp + 64 * IC);
    bf16x8 th21 = *(const bf16x8*)(thp + 64 * IC + 16);
    bf16x8 th30 = *(const bf16x8*)(thp + 96 * IC);
    bf16x8 th31 = *(const bf16x8*)(thp + 96 * IC + 16);

    const ushort* phbase = pht + (size_t)b * N_POS * IC;
    const ushort* gbase  = gcn + ((size_t)(b * IC + cl)) * N_POS;

    f32x16 y0, y1a, y2, y3, zero;
    #pragma unroll
    for (int i = 0; i < 16; i++) {
        y0[i] = 0.f; y1a[i] = 0.f; y2[i] = 0.f; y3[i] = 0.f; zero[i] = 0.f;
    }
    float su0 = 0.f, su1 = 0.f, su2 = 0.f, su3 = 0.f;

#define QTILE(T0, T1, SU, Y) do {                                              \
        f32x16 sv = __builtin_amdgcn_mfma_f32_32x32x16_bf16(ph0, T0, zero, 0, 0, 0); \
        sv = __builtin_amdgcn_mfma_f32_32x32x16_bf16(ph1, T1, sv, 0, 0, 0);    \
        uint w_[8];                                                            \
        _Pragma("unroll")                                                      \
        for (int i_ = 0; i_ < 8; i_++) {                                       \
            float p0_ = __builtin_amdgcn_exp2f(sv[2*i_]);                      \
            float p1_ = __builtin_amdgcn_exp2f(sv[2*i_+1]);                    \
            SU += p0_ + p1_;                                                   \
            w_[i_] = packtrunc(p0_, p1_);                                      \
        }                                                                      \
        uint4v a0_, a1_;                                                       \
        a0_[0] = w_[0]; a0_[1] = w_[1]; a0_[2] = w_[2]; a0_[3] = w_[3];        \
        a1_[0] = w_[4]; a1_[1] = w_[5]; a1_[2] = w_[6]; a1_[3] = w_[7];        \
        Y = __builtin_amdgcn_mfma_f32_32x32x16_bf16(                           \
            __builtin_bit_cast(bf16x8, a0_), g0, Y, 0, 0, 0);                  \
        Y = __builtin_amdgcn_mfma_f32_32x32x16_bf16(                           \
            __builtin_bit_cast(bf16x8, a1_), g1, Y, 0, 0, 0);                  \
    } while (0)

    #pragma unroll 2
    for (int mt = 0; mt < 16; ++mt) {
        int m0 = mbase + mt * 32;
        const ushort* php = phbase + ((size_t)(m0 + pcl)) * IC + 8 * h;
        bf16x8 ph0 = *(const bf16x8*)php;
        bf16x8 ph1 = *(const bf16x8*)(php + 16);
        const ushort* gp = gbase + m0 + 8 * h;
        bf16x8 g0 = *(const bf16x8*)gp;
        bf16x8 g1 = *(const bf16x8*)(gp + 16);

        QTILE(th00, th01, su0, y0);
        QTILE(th10, th11, su1, y1a);
        QTILE(th20, th21, su2, y2);
        QTILE(th30, th31, su3, y3);
    }
#undef QTILE

    su0 += __shfl_xor(su0, 32);
    su1 += __shfl_xor(su1, 32);
    su2 += __shfl_xor(su2, 32);
    su3 += __shfl_xor(su3, 32);
    if (lane < 32) {
        redD[s][0][cl] = su0; redD[s][1][cl] = su1;
        redD[s][2][cl] = su2; redD[s][3][cl] = su3;
    }

    // two-phase reduce: waves 2,3 write; waves 0,1 add; store combines [0]+[1]
    if (s >= 2) {
        #pragma unroll
        for (int r = 0; r < 16; r++) {
            int q = (r & 3) + 8 * (r >> 2) + 4 * h;
            redY[s - 2][0][q][cl] = y0[r];
            redY[s - 2][1][q][cl] = y1a[r];
            redY[s - 2][2][q][cl] = y2[r];
            redY[s - 2][3][q][cl] = y3[r];
        }
    }
    __syncthreads();
    if (s < 2) {
        #pragma unroll
        for (int r = 0; r < 16; r++) {
            int q = (r & 3) + 8 * (r >> 2) + 4 * h;
            redY[s][0][q][cl] += y0[r];
            redY[s][1][q][cl] += y1a[r];
            redY[s][2][q][cl] += y2[r];
            redY[s][3][q][cl] += y3[r];
        }
    }
    __syncthreads();

    size_t pbase = ((size_t)((b * 32 + qq) * 2 + mh)) * 4096;
    for (int i = tid; i < 4096; i += 256) {
        int t = i >> 10, rm = i & 1023;
        int q = rm >> 5, c = rm & 31;
        yp[pbase + i] = redY[0][t][q][c] + redY[1][t][q][c];
    }
    if (tid < 128) {
        int t = tid >> 5, q = tid & 31;
        dnm[((size_t)((b * 32 + qq) * 2 + mh)) * 128 + tid] =
            redD[0][t][q] + redD[1][t][q] + redD[2][t][q] + redD[3][t][q];
    }
}

// ---- Stage C+D fused: mb attention + combine + out matmul (R12-proven) -----
// block = (b, 64-n group). Phase 1: wave s -> q-tile j=s&1, k-half kh=s>>1.
// Phase 2: wave s -> 16-output slice, lane -> n (coalesced x/out).
__global__ __launch_bounds__(256) void mbout_kernel(
    const ushort* __restrict__ pht, const ushort* __restrict__ mbt,
    const ushort* __restrict__ mbb, const float* __restrict__ yp,
    const float* __restrict__ dnm, const float* __restrict__ x,
    const float* __restrict__ Ww, const float* __restrict__ Wb,
    const float* __restrict__ Wzw, const float* __restrict__ Wzb,
    float* __restrict__ out)
{
    __shared__ float sW[64][32], sWz[64][32];
    __shared__ float sb[64];
    __shared__ float ly1p[4][32][36];   // wave partials, 16B-aligned rows
    __shared__ float sumeL[4][32];
    int tid = threadIdx.x;
    int bid = blockIdx.x;
    int b = bid & 7, grp = bid >> 3;    // batch -> XCD locality; grp 0..63
    int n0 = grp * 64;

    for (int i = tid; i < 2048; i += 256) {
        sW[i >> 5][i & 31]  = Ww[i];
        sWz[i >> 5][i & 31] = Wzw[i];
    }
    if (tid < 64) sb[tid] = Wb[tid] + Wzb[tid];

    // ---- phase 1: mb attention, k-split across wave pairs ----
    int s = tid >> 6, lane = tid & 63;
    int j = s & 1, kh = s >> 1;
    int q0 = n0 + j * 32;
    int cl = lane & 31, h = lane >> 5;
    int t4 = (cl >> 2) & 3;
    int pcl = (t4 == 1 || t4 == 2) ? (cl ^ 12) : cl;

    const ushort* php = pht + ((size_t)(b * N_POS + q0 + cl)) * IC + 8 * h;
    bf16x8 qf0 = *(const bf16x8*)php;
    bf16x8 qf1 = *(const bf16x8*)(php + 16);

    f32x16 yaccA, yaccB, zero;
    #pragma unroll
    for (int i = 0; i < 16; i++) { yaccA[i] = 0.f; yaccB[i] = 0.f; zero[i] = 0.f; }
    float sume = 0.f;

    #pragma unroll
    for (int kt = 0; kt < 4; ++kt) {
        int k0 = (kh * 4 + kt) * 32;
        const ushort* ap = mbt + ((size_t)(k0 + pcl)) * IC + 8 * h;
        bf16x8 af0 = *(const bf16x8*)ap;
        bf16x8 af1 = *(const bf16x8*)(ap + 16);
        const ushort* bp = mbb + (size_t)cl * 256 + k0 + 8 * h;
        bf16x8 bf0 = *(const bf16x8*)bp;
        bf16x8 bf1 = *(const bf16x8*)(bp + 16);

        f32x16 sv = __builtin_amdgcn_mfma_f32_32x32x16_bf16(af0, qf0, zero, 0, 0, 0);
        sv = __builtin_amdgcn_mfma_f32_32x32x16_bf16(af1, qf1, sv, 0, 0, 0);

        uint w[8];
        #pragma unroll
        for (int i = 0; i < 8; i++) {
            float p0 = __builtin_amdgcn_exp2f(sv[2*i]);
            float p1 = __builtin_amdgcn_exp2f(sv[2*i+1]);
            sume += p0 + p1;
            w[i] = packtrunc(p0, p1);
        }
        uint4v a0, a1;
        a0[0] = w[0]; a0[1] = w[1]; a0[2] = w[2]; a0[3] = w[3];
        a1[0] = w[4]; a1[1] = w[5]; a1[2] = w[6]; a1[3] = w[7];

        yaccA = __builtin_amdgcn_mfma_f32_32x32x16_bf16(
            __builtin_bit_cast(bf16x8, a0), bf0, yaccA, 0, 0, 0);
        yaccB = __builtin_amdgcn_mfma_f32_32x32x16_bf16(
            __builtin_bit_cast(bf16x8, a1), bf1, yaccB, 0, 0, 0);
    }

    sume += __shfl_xor(sume, 32);          // lane q (0..31) holds partial denom
    if (lane < 32) sumeL[s][cl] = sume;
    #pragma unroll
    for (int r = 0; r < 16; r++) {
        int q = (r & 3) + 8 * (r >> 2) + 4 * h;
        ly1p[s][q][cl] = yaccA[r] + yaccB[r];
    }
    __syncthreads();

    // ---- phase 2: wave s -> outputs [obase, obase+16), lane -> n ----
    int obase = (s & 1) * 32 + (s >> 1) * 16;
    int n = n0 + lane;
    int jj = lane >> 5, q = lane & 31;

    float inv1 = 1.f / (sumeL[jj][q] + sumeL[2 + jj][q]);
    float y1v[32];
    #pragma unroll
    for (int c4 = 0; c4 < 8; c4++) {
        float4 p0 = *(const float4*)&ly1p[jj][q][c4 * 4];
        float4 p1 = *(const float4*)&ly1p[2 + jj][q][c4 * 4];
        y1v[c4*4+0] = (p0.x + p1.x) * inv1;
        y1v[c4*4+1] = (p0.y + p1.y) * inv1;
        y1v[c4*4+2] = (p0.z + p1.z) * inv1;
        y1v[c4*4+3] = (p0.w + p1.w) * inv1;
    }

    int qt = n >> 5;                   // global 32-q tile 0..127
    int qqn = qt >> 2, tt = qt & 3;
    size_t pb = ((size_t)((b * 32 + qqn) * 2)) * 4096;
    size_t db = ((size_t)((b * 32 + qqn) * 2)) * 128;
    float den = dnm[db + tt * 32 + q] + dnm[db + 128 + tt * 32 + q];
    float inv = 1.f / den;
    const float* yp0 = yp + pb + tt * 1024 + q * 32;
    const float* yp1 = yp0 + 4096;
    float yv[32];
    #pragma unroll
    for (int c4 = 0; c4 < 8; c4++) {
        float4 v0 = ((const float4*)yp0)[c4];
        float4 v1 = ((const float4*)yp1)[c4];
        yv[c4*4+0] = (v0.x + v1.x) * inv;
        yv[c4*4+1] = (v0.y + v1.y) * inv;
        yv[c4*4+2] = (v0.z + v1.z) * inv;
        yv[c4*4+3] = (v0.w + v1.w) * inv;
    }

    const float* xb = x   + ((size_t)(b * C_IN + obase)) * N_POS + n;
    float*       ob = out + ((size_t)(b * C_IN + obase)) * N_POS + n;
    for (int o = 0; o < 16; o++) {
        float acc = sb[obase + o] + xb[(size_t)o * N_POS];
        const float4* w4  = (const float4*)sW[obase + o];
        const float4* wz4 = (const float4*)sWz[obase + o];
        #pragma unroll
        for (int c4 = 0; c4 < 8; c4++) {
            float4 a = w4[c4], z = wz4[c4];
            acc += a.x * yv[c4*4+0] + a.y * yv[c4*4+1] + a.z * yv[c4*4+2] + a.w * yv[c4*4+3];
            acc += z.x * y1v[c4*4+0] + z.y * y1v[c4*4+1] + z.z * y1v[c4*4+2] + z.w * y1v[c4*4+3];
        }
        ob[(size_t)o * N_POS] = acc;
    }
}

extern "C" void kernel_launch(void* const* d_in, const int* in_sizes, int n_in,
                              void* d_out, int out_size, void* d_ws, size_t ws_size,
                              hipStream_t stream) {
    const float* x    = (const float*)d_in[0];
    const float* g_w  = (const float*)d_in[1];
    const float* g_b  = (const float*)d_in[2];
    const float* th_w = (const float*)d_in[3];
    const float* th_b = (const float*)d_in[4];
    const float* ph_w = (const float*)d_in[5];
    const float* ph_b = (const float*)d_in[6];
    const float* W_w  = (const float*)d_in[7];
    const float* W_b  = (const float*)d_in[8];
    const float* Wz_w = (const float*)d_in[9];
    const float* Wz_b = (const float*)d_in[10];
    const float* mb   = (const float*)d_in[11];
    float* out = (float*)d_out;

    char* w = (char*)d_ws;
    ushort* tht = (ushort*)w;                        // 2 MB
    ushort* pht = (ushort*)(w + (2u << 20));         // 2 MB
    ushort* gcn = (ushort*)(w + (4u << 20));         // 2 MB
    ushort* mbt = (ushort*)(w + (6u << 20));         // 16 KB
    ushort* mbb = (ushort*)(w + (6u << 20) + 16384); // 16 KB
    float*  yp  = (float*)(w + (9u << 20));          // 8 MB
    float*  dnm = (float*)(w + (17u << 20));         // 256 KB

    proj_kernel<<<dim3(256, 12), 128, 0, stream>>>(x, g_w, g_b, th_w, th_b,
                                                   ph_w, ph_b, mb,
                                                   gcn, tht, pht, mbt, mbb);
    attn_kernel<<<512, 256, 0, stream>>>(tht, pht, gcn, yp, dnm);
    mbout_kernel<<<512, 256, 0, stream>>>(pht, mbt, mbb, yp, dnm, x,
                                          W_w, W_b, Wz_w, Wz_b, out);
}